// Round 1
// baseline (1212.905 us; speedup 1.0000x reference)
//
#include <hip/hip_runtime.h>
#include <hip/hip_bf16.h>
#include <stdint.h>

typedef __attribute__((ext_vector_type(8))) short s16x8;
typedef __attribute__((ext_vector_type(4))) float f32x4;

__device__ __forceinline__ unsigned short f2bf(float f) {
    unsigned int u = __float_as_uint(f);
    u += 0x7fffu + ((u >> 16) & 1u);   // round-to-nearest-even
    return (unsigned short)(u >> 16);
}

__device__ __forceinline__ void load16_lds(const unsigned short* g, unsigned short* l) {
    __builtin_amdgcn_global_load_lds(
        (const __attribute__((address_space(1))) unsigned int*)g,
        (__attribute__((address_space(3))) unsigned int*)l,
        16, 0, 0);
}

__device__ __forceinline__ void store_out(unsigned short* p, float v) { *p = f2bf(v); }
__device__ __forceinline__ void store_out(float* p, float v) { *p = v; }

// ---------------- fp32 -> bf16 convert ----------------
__global__ __launch_bounds__(256) void cvt_bf16(const float* __restrict__ s,
                                                unsigned short* __restrict__ d, int n4) {
    int i = blockIdx.x * 256 + threadIdx.x;
    int stride = gridDim.x * 256;
    for (; i < n4; i += stride) {
        float4 v = ((const float4*)s)[i];
        ushort4 o;
        o.x = f2bf(v.x); o.y = f2bf(v.y); o.z = f2bf(v.z); o.w = f2bf(v.w);
        ((ushort4*)d)[i] = o;
    }
}

// ---------------- NT GEMM: C[M,N] = A[M,K] * B[N,K]^T (+bias) ----------------
// 128x128 tile, BK=32, 256 threads (4 waves, each 64x64), 16x16x32 bf16 MFMA.
template <typename OutT>
__global__ __launch_bounds__(256) void gemm_bt(
    const unsigned short* __restrict__ A, const unsigned short* __restrict__ B,
    OutT* __restrict__ C, const float* __restrict__ bias,
    int M, int N, int K,
    long long strideA, long long strideB, long long strideC)
{
    __shared__ unsigned short lA[128 * 32];
    __shared__ unsigned short lB[128 * 32];

    const int batch = blockIdx.y;
    A += (long long)batch * strideA;
    B += (long long)batch * strideB;
    C += (long long)batch * strideC;

    const int ntn = N >> 7;
    const int tm = blockIdx.x / ntn;
    const int tn = blockIdx.x % ntn;

    const int tid = threadIdx.x;
    const int wave = tid >> 6;
    const int lane = tid & 63;
    const int quad = lane >> 4;
    const int l16 = lane & 15;

    // staging: thread's two 16B loads; LDS tile is row-major [128][32], exact lane order
    const int col = (lane & 3) * 8;
    const int idx0 = (wave * 2 + 0) * 64 + lane;
    const int idx1 = (wave * 2 + 1) * 64 + lane;
    const unsigned short* gA0 = A + (long long)(tm * 128 + (idx0 >> 2)) * K + col;
    const unsigned short* gA1 = A + (long long)(tm * 128 + (idx1 >> 2)) * K + col;
    const unsigned short* gB0 = B + (long long)(tn * 128 + (idx0 >> 2)) * K + col;
    const unsigned short* gB1 = B + (long long)(tn * 128 + (idx1 >> 2)) * K + col;
    unsigned short* dA0 = lA + (wave * 2 + 0) * 512;
    unsigned short* dA1 = lA + (wave * 2 + 1) * 512;
    unsigned short* dB0 = lB + (wave * 2 + 0) * 512;
    unsigned short* dB1 = lB + (wave * 2 + 1) * 512;

    const int wm = (wave >> 1) * 64;
    const int wn = (wave & 1) * 64;

    f32x4 acc[4][4] = {};

    for (int k0 = 0; k0 < K; k0 += 32) {
        __syncthreads();                       // prev iter's LDS reads done
        load16_lds(gA0, dA0);
        load16_lds(gA1, dA1);
        load16_lds(gB0, dB0);
        load16_lds(gB1, dB1);
        gA0 += 32; gA1 += 32; gB0 += 32; gB1 += 32;
        __syncthreads();                       // compiler drains vmcnt before barrier

        s16x8 af[4], bfr[4];
#pragma unroll
        for (int i = 0; i < 4; ++i)
            af[i] = *(const s16x8*)&lA[(wm + i * 16 + l16) * 32 + quad * 8];
#pragma unroll
        for (int j = 0; j < 4; ++j)
            bfr[j] = *(const s16x8*)&lB[(wn + j * 16 + l16) * 32 + quad * 8];
#pragma unroll
        for (int i = 0; i < 4; ++i)
#pragma unroll
            for (int j = 0; j < 4; ++j)
                acc[i][j] = __builtin_amdgcn_mfma_f32_16x16x32_bf16(af[i], bfr[j], acc[i][j], 0, 0, 0);
    }

    // epilogue: C/D layout col=lane&15, row=quad*4+reg
#pragma unroll
    for (int i = 0; i < 4; ++i) {
        const int m0 = tm * 128 + wm + i * 16 + quad * 4;
#pragma unroll
        for (int j = 0; j < 4; ++j) {
            const int n = tn * 128 + wn + j * 16 + l16;
            const float bv = bias ? bias[n] : 0.0f;
#pragma unroll
            for (int r = 0; r < 4; ++r) {
                float v = acc[i][j][r] + bv;
                store_out(&C[(long long)(m0 + r) * N + n], v);
            }
        }
    }
}

// ---------------- row softmax in-place on bf16 scores, row length 2048 ----------------
__global__ __launch_bounds__(256) void softmax_inplace(unsigned short* __restrict__ S, float scale) {
    const long long row = blockIdx.x;
    unsigned short* p = S + row * 2048;
    const int t = threadIdx.x;
    const int wave = t >> 6, lane = t & 63;

    uint4 raw = ((const uint4*)p)[t];        // 8 bf16 per thread
    unsigned int w[4] = { raw.x, raw.y, raw.z, raw.w };
    float x[8];
#pragma unroll
    for (int i = 0; i < 4; ++i) {
        x[2 * i]     = __uint_as_float(w[i] << 16);
        x[2 * i + 1] = __uint_as_float(w[i] & 0xffff0000u);
    }

    float mx = x[0];
#pragma unroll
    for (int i = 1; i < 8; ++i) mx = fmaxf(mx, x[i]);
    for (int o = 32; o > 0; o >>= 1) mx = fmaxf(mx, __shfl_xor(mx, o));
    __shared__ float rm[4], rs[4];
    if (lane == 0) rm[wave] = mx;
    __syncthreads();
    mx = fmaxf(fmaxf(rm[0], rm[1]), fmaxf(rm[2], rm[3]));

    float e[8], sum = 0.0f;
#pragma unroll
    for (int i = 0; i < 8; ++i) { e[i] = __expf((x[i] - mx) * scale); sum += e[i]; }
    for (int o = 32; o > 0; o >>= 1) sum += __shfl_xor(sum, o);
    if (lane == 0) rs[wave] = sum;
    __syncthreads();
    const float inv = 1.0f / (rs[0] + rs[1] + rs[2] + rs[3]);

    uint4 out;
    out.x = (unsigned)f2bf(e[0] * inv) | ((unsigned)f2bf(e[1] * inv) << 16);
    out.y = (unsigned)f2bf(e[2] * inv) | ((unsigned)f2bf(e[3] * inv) << 16);
    out.z = (unsigned)f2bf(e[4] * inv) | ((unsigned)f2bf(e[5] * inv) << 16);
    out.w = (unsigned)f2bf(e[6] * inv) | ((unsigned)f2bf(e[7] * inv) << 16);
    ((uint4*)p)[t] = out;
}

// ---------------- bf16 transpose per batch: [2048,1024] -> [1024,2048] ----------------
__global__ void transpose_bf16(const unsigned short* __restrict__ src,
                               unsigned short* __restrict__ dst) {
    __shared__ unsigned short t[32][33];
    const long long b = blockIdx.z;
    const unsigned short* s = src + b * 2097152LL;
    unsigned short* d = dst + b * 2097152LL;
    const int c0 = blockIdx.x * 32;   // src col (0..1023)
    const int r0 = blockIdx.y * 32;   // src row (0..2047)
    const int tx = threadIdx.x, ty = threadIdx.y;
#pragma unroll
    for (int i = 0; i < 32; i += 8)
        t[ty + i][tx] = s[(long long)(r0 + ty + i) * 1024 + c0 + tx];
    __syncthreads();
#pragma unroll
    for (int i = 0; i < 32; i += 8)
        d[(long long)(c0 + ty + i) * 2048 + r0 + tx] = t[tx][ty + i];
}

extern "C" void kernel_launch(void* const* d_in, const int* in_sizes, int n_in,
                              void* d_out, int out_size, void* d_ws, size_t ws_size,
                              hipStream_t stream) {
    const float* query = (const float*)d_in[0];   // [16,2048,1024]
    const float* key   = (const float*)d_in[1];   // [16,2048,768]
    const float* value = (const float*)d_in[2];   // [16,2048,768]
    const float* Wq    = (const float*)d_in[3];   // [1024,1024]
    const float* bq    = (const float*)d_in[4];
    const float* Wk    = (const float*)d_in[5];   // [1024,768]
    const float* bk    = (const float*)d_in[6];
    const float* Wv    = (const float*)d_in[7];   // [1024,768]
    const float* bv    = (const float*)d_in[8];

    char* ws = (char*)d_ws;
    // region 0 (0 .. 167,772,160): bf16 inputs; later aliased by S (134,217,728 B)
    unsigned short* qin = (unsigned short*)ws;                    // 33,554,432 elems
    unsigned short* kin = qin + 33554432LL;                       // 25,165,824 elems
    unsigned short* vin = kin + 25165824LL;                       // 25,165,824 elems
    unsigned short* Sb  = (unsigned short*)ws;                    // alias (after proj GEMMs)
    // region 1: bf16 weights
    unsigned short* Wqb = (unsigned short*)(ws + 167772160LL);    // 1,048,576 elems
    unsigned short* Wkb = Wqb + 1048576LL;                        // 786,432
    unsigned short* Wvb = Wkb + 786432LL;                         // 786,432
    // region 2: projections
    unsigned short* qp  = (unsigned short*)(ws + 173015040LL);    // 33,554,432 elems
    unsigned short* kp  = qp + 33554432LL;
    unsigned short* vp  = kp + 33554432LL;
    unsigned short* vT  = qp;                                     // alias (after S GEMM)
    // total ws use: 374,341,632 bytes

    dim3 blk(256);

    // 1) converts
    cvt_bf16<<<2048, blk, 0, stream>>>(query, qin, 33554432 / 4);
    cvt_bf16<<<2048, blk, 0, stream>>>(key,   kin, 25165824 / 4);
    cvt_bf16<<<2048, blk, 0, stream>>>(value, vin, 25165824 / 4);
    cvt_bf16<<<256,  blk, 0, stream>>>(Wq, Wqb, 1048576 / 4);
    cvt_bf16<<<256,  blk, 0, stream>>>(Wk, Wkb, 786432 / 4);
    cvt_bf16<<<256,  blk, 0, stream>>>(Wv, Wvb, 786432 / 4);

    // 2) projections: [32768,K] x [1024,K]^T + bias -> bf16
    gemm_bt<unsigned short><<<dim3(2048, 1), blk, 0, stream>>>(qin, Wqb, qp, bq, 32768, 1024, 1024, 0, 0, 0);
    gemm_bt<unsigned short><<<dim3(2048, 1), blk, 0, stream>>>(kin, Wkb, kp, bk, 32768, 1024, 768, 0, 0, 0);
    gemm_bt<unsigned short><<<dim3(2048, 1), blk, 0, stream>>>(vin, Wvb, vp, bv, 32768, 1024, 768, 0, 0, 0);

    // 3) S = q . k^T  (batched x16), bf16 scores
    gemm_bt<unsigned short><<<dim3(256, 16), blk, 0, stream>>>(qp, kp, Sb, nullptr, 2048, 2048, 1024,
                                                               2097152LL, 2097152LL, 4194304LL);

    // 4) transpose v_p -> vT (after S GEMM so vT can overwrite qp)
    transpose_bf16<<<dim3(32, 64, 16), dim3(32, 8), 0, stream>>>(vp, vT);

    // 5) softmax rows in-place (scale = OUT_DIM^-0.5 = 1/32)
    softmax_inplace<<<32768, blk, 0, stream>>>(Sb, 0.03125f);

    // 6) O = P . vT (batched x16), fp32 out
    gemm_bt<float><<<dim3(128, 16), blk, 0, stream>>>(Sb, vT, (float*)d_out, nullptr, 2048, 1024, 2048,
                                                      4194304LL, 2097152LL, 2097152LL);
}

// Round 2
// 1136.215 us; speedup vs baseline: 1.0675x; 1.0675x over previous
//
#include <hip/hip_runtime.h>
#include <hip/hip_bf16.h>
#include <stdint.h>

typedef __attribute__((ext_vector_type(8))) short s16x8;
typedef __attribute__((ext_vector_type(4))) float f32x4;

__device__ __forceinline__ unsigned short f2bf(float f) {
    unsigned int u = __float_as_uint(f);
    u += 0x7fffu + ((u >> 16) & 1u);   // round-to-nearest-even
    return (unsigned short)(u >> 16);
}

__device__ __forceinline__ void load16_lds(const unsigned short* g, unsigned short* l) {
    __builtin_amdgcn_global_load_lds(
        (const __attribute__((address_space(1))) unsigned int*)g,
        (__attribute__((address_space(3))) unsigned int*)l,
        16, 0, 0);
}

// ---------------- fused fp32 -> bf16 convert over 3 arrays (float4 units) ----------------
__global__ __launch_bounds__(256) void cvt3(
    const float* __restrict__ a, unsigned short* __restrict__ da, int na,
    const float* __restrict__ b, unsigned short* __restrict__ db, int nb,
    const float* __restrict__ c, unsigned short* __restrict__ dc, int nc)
{
    const int total = na + nb + nc;
    for (int i = blockIdx.x * 256 + threadIdx.x; i < total; i += gridDim.x * 256) {
        const float* s; unsigned short* d; int j = i;
        if (j < na)            { s = a; d = da; }
        else if (j < na + nb)  { s = b; d = db; j -= na; }
        else                   { s = c; d = dc; j -= na + nb; }
        float4 v = ((const float4*)s)[j];
        ushort4 o;
        o.x = f2bf(v.x); o.y = f2bf(v.y); o.z = f2bf(v.z); o.w = f2bf(v.w);
        ((ushort4*)d)[j] = o;
    }
}

__global__ __launch_bounds__(256) void recip_k(float* __restrict__ p, int n) {
    int i = blockIdx.x * 256 + threadIdx.x;
    if (i < n) p[i] = 1.0f / p[i];
}

// ---------------- NT GEMM: C[M,N] = A[M,K] * B[N,K]^T, epilogue variants ----------------
// MODE 0: bf16 out + bias (q/k projections)
// MODE 1: bf16 out + bias, TRANSPOSED store (v projection -> vT[batch][1024][2048])
// MODE 2: bf16 out = exp(acc*scale), atomicAdd row sums (S = qk^T)
// MODE 3: f32 out = acc * rowinv[row]  (O = P~ . vT / rowsum)
// 128x128 tile, BK=32, 256 threads (4 waves, each 64x64), 16x16x32 bf16 MFMA.
template <int MODE>
__global__ __launch_bounds__(256) void gemm_bt(
    const unsigned short* __restrict__ A, const unsigned short* __restrict__ B,
    void* __restrict__ Cv, const float* __restrict__ bias,
    float* __restrict__ rowsum, const float* __restrict__ rowinv, float scale,
    int M, int N, int K,
    long long strideA, long long strideB, long long strideC)
{
    __shared__ unsigned short sh[8192];       // 16 KB: lA (4096) + lB (4096)
    unsigned short* lA = sh;
    unsigned short* lB = sh + 4096;

    const int batch = blockIdx.y;
    A += (long long)batch * strideA;
    B += (long long)batch * strideB;

    const int ntn = N >> 7;
    const int tm = blockIdx.x / ntn;
    const int tn = blockIdx.x % ntn;

    const int tid = threadIdx.x;
    const int wave = tid >> 6;
    const int lane = tid & 63;
    const int quad = lane >> 4;
    const int l16 = lane & 15;

    // staging: thread's two 16B loads per operand; LDS row-major [128][32]
    const int col = (lane & 3) * 8;
    const int idx0 = (wave * 2 + 0) * 64 + lane;
    const int idx1 = (wave * 2 + 1) * 64 + lane;
    const unsigned short* gA0 = A + (long long)(tm * 128 + (idx0 >> 2)) * K + col;
    const unsigned short* gA1 = A + (long long)(tm * 128 + (idx1 >> 2)) * K + col;
    const unsigned short* gB0 = B + (long long)(tn * 128 + (idx0 >> 2)) * K + col;
    const unsigned short* gB1 = B + (long long)(tn * 128 + (idx1 >> 2)) * K + col;
    unsigned short* dA0 = lA + (wave * 2 + 0) * 512;
    unsigned short* dA1 = lA + (wave * 2 + 1) * 512;
    unsigned short* dB0 = lB + (wave * 2 + 0) * 512;
    unsigned short* dB1 = lB + (wave * 2 + 1) * 512;

    const int wm = (wave >> 1) * 64;
    const int wn = (wave & 1) * 64;

    f32x4 acc[4][4] = {};

    for (int k0 = 0; k0 < K; k0 += 32) {
        __syncthreads();
        load16_lds(gA0, dA0);
        load16_lds(gA1, dA1);
        load16_lds(gB0, dB0);
        load16_lds(gB1, dB1);
        gA0 += 32; gA1 += 32; gB0 += 32; gB1 += 32;
        __syncthreads();

        s16x8 af[4], bfr[4];
#pragma unroll
        for (int i = 0; i < 4; ++i)
            af[i] = *(const s16x8*)&lA[(wm + i * 16 + l16) * 32 + quad * 8];
#pragma unroll
        for (int j = 0; j < 4; ++j)
            bfr[j] = *(const s16x8*)&lB[(wn + j * 16 + l16) * 32 + quad * 8];
#pragma unroll
        for (int i = 0; i < 4; ++i)
#pragma unroll
            for (int j = 0; j < 4; ++j)
                acc[i][j] = __builtin_amdgcn_mfma_f32_16x16x32_bf16(af[i], bfr[j], acc[i][j], 0, 0, 0);
    }

    // C/D layout: col = lane&15, row = quad*4 + reg
    if (MODE == 0) {
        unsigned short* C = (unsigned short*)Cv + (long long)batch * strideC;
#pragma unroll
        for (int i = 0; i < 4; ++i) {
            const int m0 = tm * 128 + wm + i * 16 + quad * 4;
#pragma unroll
            for (int j = 0; j < 4; ++j) {
                const int n = tn * 128 + wn + j * 16 + l16;
                const float bv = bias[n];
#pragma unroll
                for (int r = 0; r < 4; ++r)
                    C[(long long)(m0 + r) * N + n] = f2bf(acc[i][j][r] + bv);
            }
        }
    } else if (MODE == 2) {
        unsigned short* C = (unsigned short*)Cv + (long long)batch * strideC;
        float psum[4][4];
#pragma unroll
        for (int i = 0; i < 4; ++i)
#pragma unroll
            for (int r = 0; r < 4; ++r) psum[i][r] = 0.0f;
#pragma unroll
        for (int i = 0; i < 4; ++i) {
            const int m0 = tm * 128 + wm + i * 16 + quad * 4;
#pragma unroll
            for (int j = 0; j < 4; ++j) {
                const int n = tn * 128 + wn + j * 16 + l16;
#pragma unroll
                for (int r = 0; r < 4; ++r) {
                    float e = __expf(acc[i][j][r] * scale);
                    C[(long long)(m0 + r) * N + n] = f2bf(e);
                    psum[i][r] += e;
                }
            }
        }
        // reduce over the 16 l16 lanes (same rows, different cols), then atomic
        float* rs = rowsum + (long long)batch * 2048;
#pragma unroll
        for (int i = 0; i < 4; ++i) {
            const int m0 = tm * 128 + wm + i * 16 + quad * 4;
#pragma unroll
            for (int r = 0; r < 4; ++r) {
                float v = psum[i][r];
                v += __shfl_xor(v, 1);
                v += __shfl_xor(v, 2);
                v += __shfl_xor(v, 4);
                v += __shfl_xor(v, 8);
                if (l16 == 0) atomicAdd(&rs[m0 + r], v);
            }
        }
    } else if (MODE == 3) {
        float* C = (float*)Cv + (long long)batch * strideC;
        const float* ri = rowinv + (long long)batch * 2048;
#pragma unroll
        for (int i = 0; i < 4; ++i) {
            const int m0 = tm * 128 + wm + i * 16 + quad * 4;
            const float4 inv4 = *(const float4*)&ri[m0];
#pragma unroll
            for (int j = 0; j < 4; ++j) {
                const int n = tn * 128 + wn + j * 16 + l16;
                C[(long long)(m0 + 0) * N + n] = acc[i][j][0] * inv4.x;
                C[(long long)(m0 + 1) * N + n] = acc[i][j][1] * inv4.y;
                C[(long long)(m0 + 2) * N + n] = acc[i][j][2] * inv4.z;
                C[(long long)(m0 + 3) * N + n] = acc[i][j][3] * inv4.w;
            }
        }
    } else { // MODE 1: transposed bf16 store through LDS.
        // Only used for v-proj: M=32768 (batch*2048+s), N=1024 (o).
        // Output vT[batch][o][s]: row len 2048, batch stride 1024*2048.
        const int batch_o = (tm * 128) >> 11;
        const int s0 = (tm * 128) & 2047;
        unsigned short* out = (unsigned short*)Cv + (long long)batch_o * 2097152LL + s0;
        const int STR = 132;  // padded row stride (shorts) -> conflict-light scalar writes
#pragma unroll
        for (int c = 0; c < 4; ++c) {           // chunk: 32 o-rows
            __syncthreads();                    // sh free (K-loop or prev chunk done)
            if ((wn >> 6) == (c >> 1)) {
                const int jbase = (c & 1) * 2;
#pragma unroll
                for (int jj = 0; jj < 2; ++jj) {
                    const int j = jbase + jj;
                    const int nnl = j * 16 + l16 - (c & 1) * 32;        // 0..31
                    const float bv = bias[tn * 128 + wn + j * 16 + l16];
#pragma unroll
                    for (int i = 0; i < 4; ++i) {
                        const int mmb = wm + i * 16 + quad * 4;
#pragma unroll
                        for (int r = 0; r < 4; ++r)
                            sh[nnl * STR + mmb + r] = f2bf(acc[i][j][r] + bv);
                    }
                }
            }
            __syncthreads();
            // copy 32 rows x 128 shorts (8 B per thread per pass, coalesced 256 B rows)
#pragma unroll
            for (int rr = 0; rr < 4; ++rr) {
                const int row = rr * 8 + (tid >> 5);     // 0..31
                const int cs = (tid & 31) * 4;           // short offset in row
                unsigned long long v8 = *(const unsigned long long*)&sh[row * STR + cs];
                *(unsigned long long*)&out[(long long)(tn * 128 + c * 32 + row) * 2048 + cs] = v8;
            }
        }
    }
}

extern "C" void kernel_launch(void* const* d_in, const int* in_sizes, int n_in,
                              void* d_out, int out_size, void* d_ws, size_t ws_size,
                              hipStream_t stream) {
    const float* query = (const float*)d_in[0];   // [16,2048,1024]
    const float* key   = (const float*)d_in[1];   // [16,2048,768]
    const float* value = (const float*)d_in[2];   // [16,2048,768]
    const float* Wq    = (const float*)d_in[3];   // [1024,1024]
    const float* bq    = (const float*)d_in[4];
    const float* Wk    = (const float*)d_in[5];   // [1024,768]
    const float* bk    = (const float*)d_in[6];
    const float* Wv    = (const float*)d_in[7];   // [1024,768]
    const float* bv    = (const float*)d_in[8];

    char* ws = (char*)d_ws;
    // region 0 [0, 167772160): bf16 inputs; later aliased by Sb (134217728 B) + rowsum
    unsigned short* qin = (unsigned short*)ws;                    // 33,554,432 elems
    unsigned short* kin = qin + 33554432LL;                       // 25,165,824
    unsigned short* vin = kin + 25165824LL;                       // 25,165,824
    unsigned short* Sb  = (unsigned short*)ws;                    // alias (after projections)
    float* rowsum = (float*)(ws + 134217728LL);                   // 32768 f32 (dead vin tail)
    // region 1: bf16 weights
    unsigned short* Wqb = (unsigned short*)(ws + 167772160LL);    // 1,048,576
    unsigned short* Wkb = Wqb + 1048576LL;                        // 786,432
    unsigned short* Wvb = Wkb + 786432LL;                         // 786,432
    // region 2: projections
    unsigned short* qp  = (unsigned short*)(ws + 173015040LL);    // 33,554,432
    unsigned short* kp  = qp + 33554432LL;                        // 33,554,432
    unsigned short* vT  = kp + 33554432LL;                        // 33,554,432 ([16][1024][2048])

    dim3 blk(256);

    // 1) converts (2 launches)
    cvt3<<<8192, blk, 0, stream>>>(query, qin, 33554432 / 4,
                                   key,   kin, 25165824 / 4,
                                   value, vin, 25165824 / 4);
    cvt3<<<2560, blk, 0, stream>>>(Wq, Wqb, 1048576 / 4,
                                   Wk, Wkb, 786432 / 4,
                                   Wv, Wvb, 786432 / 4);

    // 2) projections
    gemm_bt<0><<<dim3(2048, 1), blk, 0, stream>>>(qin, Wqb, qp, bq, nullptr, nullptr, 0.f,
                                                  32768, 1024, 1024, 0, 0, 0);
    gemm_bt<0><<<dim3(2048, 1), blk, 0, stream>>>(kin, Wkb, kp, bk, nullptr, nullptr, 0.f,
                                                  32768, 1024, 768, 0, 0, 0);
    gemm_bt<1><<<dim3(2048, 1), blk, 0, stream>>>(vin, Wvb, vT, bv, nullptr, nullptr, 0.f,
                                                  32768, 1024, 768, 0, 0, 0);

    // 3) zero row sums (after v-proj consumed vin; memset node is capture-safe)
    hipMemsetAsync(rowsum, 0, 32768 * sizeof(float), stream);

    // 4) S~ = exp(q.k^T * scale), bf16, + row sums  (batched x16)
    gemm_bt<2><<<dim3(256, 16), blk, 0, stream>>>(qp, kp, Sb, nullptr, rowsum, nullptr, 0.03125f,
                                                  2048, 2048, 1024, 2097152LL, 2097152LL, 4194304LL);

    // 5) rowsum -> 1/rowsum
    recip_k<<<128, blk, 0, stream>>>(rowsum, 32768);

    // 6) O = (S~ . vT) * rowinv  (batched x16), fp32 out
    gemm_bt<3><<<dim3(128, 16), blk, 0, stream>>>(Sb, vT, (float*)d_out, nullptr, nullptr, rowsum, 1.0f,
                                                  2048, 1024, 2048, 4194304LL, 2097152LL, 2097152LL);
}